// Round 15
// baseline (1047.010 us; speedup 1.0000x reference)
//
#include <hip/hip_runtime.h>
#include <math.h>

#define Bn 128
#define Tn 512
#define Dn 32
#define Hn 128
#define Gn 512   // 4*H
#define Ln 3

// LDS-only barrier: does NOT drain vmcnt.
#define BAR_LDS() asm volatile("s_waitcnt lgkmcnt(0)\n\ts_barrier" ::: "memory")

typedef _Float16 h2 __attribute__((ext_vector_type(2)));
typedef _Float16 h4 __attribute__((ext_vector_type(4)));
typedef _Float16 half8 __attribute__((ext_vector_type(8)));   // MFMA A/B frag
typedef float f32x4 __attribute__((ext_vector_type(4)));      // MFMA acc

__device__ __forceinline__ float dot2(h2 a, h2 b, float c) {
    return __builtin_amdgcn_fdot2(a, b, c, false);
}
__device__ __forceinline__ h2 pkh(float a, float b) {
    h2 r; r.x = (_Float16)a; r.y = (_Float16)b; return r;
}
__device__ __forceinline__ float sigm(float x) {
    return __builtin_amdgcn_rcpf(1.f + __expf(-x));
}
__device__ __forceinline__ float tanh_fast(float x) {
    return 1.f - 2.f * __builtin_amdgcn_rcpf(1.f + __expf(2.f * x));
}

// pair-local butterfly add via DPP quad_perm(1,0,3,2): lanes 2i <-> 2i+1
#define DPPADD(a, CTRL) { \
    int _t = __builtin_amdgcn_update_dpp(0, __builtin_bit_cast(int, a), \
                                         CTRL, 0xF, 0xF, true); \
    a += __builtin_bit_cast(float, _t); }

#define KEEPH(x) asm volatile("" : "+v"(x))
#define LD8H(p) (*(const half8*)(p))
#define H2OF(V, i) (((const h2*)&(V))[i])

#define DECL16(P, R) \
  h2 P##0=pkh((R)[0],(R)[1]),   P##1=pkh((R)[2],(R)[3]),   P##2=pkh((R)[4],(R)[5]),   P##3=pkh((R)[6],(R)[7]),   \
     P##4=pkh((R)[8],(R)[9]),   P##5=pkh((R)[10],(R)[11]), P##6=pkh((R)[12],(R)[13]), P##7=pkh((R)[14],(R)[15]), \
     P##8=pkh((R)[16],(R)[17]), P##9=pkh((R)[18],(R)[19]), P##10=pkh((R)[20],(R)[21]),P##11=pkh((R)[22],(R)[23]),\
     P##12=pkh((R)[24],(R)[25]),P##13=pkh((R)[26],(R)[27]),P##14=pkh((R)[28],(R)[29]),P##15=pkh((R)[30],(R)[31]);
#define KEEP16(P) \
  KEEPH(P##0); KEEPH(P##1); KEEPH(P##2); KEEPH(P##3); KEEPH(P##4); KEEPH(P##5); \
  KEEPH(P##6); KEEPH(P##7); KEEPH(P##8); KEEPH(P##9); KEEPH(P##10); KEEPH(P##11); \
  KEEPH(P##12); KEEPH(P##13); KEEPH(P##14); KEEPH(P##15);

#define EXTRACT16(P, A, B, C, D) \
  h2 P##0 = H2OF(A,0), P##1 = H2OF(A,1), P##2  = H2OF(A,2), P##3  = H2OF(A,3), \
     P##4 = H2OF(B,0), P##5 = H2OF(B,1), P##6  = H2OF(B,2), P##7  = H2OF(B,3), \
     P##8 = H2OF(C,0), P##9 = H2OF(C,1), P##10 = H2OF(C,2), P##11 = H2OF(C,3), \
     P##12= H2OF(D,0), P##13= H2OF(D,1), P##14 = H2OF(D,2), P##15 = H2OF(D,3);

// split-accumulator dots: chain depth 8 per partial instead of 32.
#define DOTA_P(j, I_, F_, G_, O_) { \
    I_ = dot2(hvA##j, wiA##j, I_);  F_ = dot2(hvA##j, wfA##j, F_); \
    G_ = dot2(hvA##j, wgA##j, G_);  O_ = dot2(hvA##j, woA##j, O_); }
#define DOTB_P(j, I_, F_, G_, O_) { \
    I_ = dot2(hvB##j, wiB##j, I_);  F_ = dot2(hvB##j, wfB##j, F_); \
    G_ = dot2(hvB##j, wgB##j, G_);  O_ = dot2(hvB##j, woB##j, O_); }

// ---------------------------------------------------------------------------
// MFMA GEMM with inline dtype conversion. TA = A dtype (fp32 x / fp16 hs),
// W always fp32. Output: QUAD-INTERLEAVED pre4[((m>>2)*Gn + g)*4 + (m&3)]
// so the scan loads one b64 per gate per FOUR ticks. Layouts HW-verified.
// ---------------------------------------------------------------------------
template<typename TA>
__global__ __launch_bounds__(256) void gemm_pre(
    const TA* __restrict__ A, int K, int rowStrideB, int t0, int tlog,
    const float* __restrict__ W,
    const float* __restrict__ bi, const float* __restrict__ bh,
    _Float16* __restrict__ C)
{
    __shared__ h2 As2[64][20];
    __shared__ h2 Bs2[64][20];
    const int tid  = threadIdx.x;
    const int row0 = blockIdx.x * 64;
    const int col0 = blockIdx.y * 64;
    const int w    = tid >> 6;
    const int lane = tid & 63;
    const int qm   = (w >> 1) * 32;
    const int qn   = (w & 1) * 32;
    const int fm   = lane & 15;
    const int fq   = lane >> 4;
    const int tmask = (1 << tlog) - 1;
    const int lrow = tid >> 2;
    const int lk   = (tid & 3) * 8;

    f32x4 acc00 = {0,0,0,0}, acc01 = {0,0,0,0};
    f32x4 acc10 = {0,0,0,0}, acc11 = {0,0,0,0};

    for (int k0 = 0; k0 < K; k0 += 32) {
        {
            int rg = row0 + lrow;
            int b_idx = rg >> tlog, tt = rg & tmask;
            const TA* ap = A + (size_t)b_idx * rowStrideB +
                           (size_t)(t0 + tt) * K + (k0 + lk);
            if constexpr (sizeof(TA) == 2) {
                *(float4*)&As2[lrow][(tid & 3) * 4] = *(const float4*)ap;
            } else {
                float4 va = *(const float4*)ap;
                float4 vb = *(const float4*)(ap + 4);
                float4 o;
                ((h2*)&o)[0] = pkh(va.x, va.y);
                ((h2*)&o)[1] = pkh(va.z, va.w);
                ((h2*)&o)[2] = pkh(vb.x, vb.y);
                ((h2*)&o)[3] = pkh(vb.z, vb.w);
                *(float4*)&As2[lrow][(tid & 3) * 4] = o;
            }
            const float* wp = W + (size_t)(col0 + lrow) * K + (k0 + lk);
            float4 wa = *(const float4*)wp;
            float4 wb = *(const float4*)(wp + 4);
            float4 ow;
            ((h2*)&ow)[0] = pkh(wa.x, wa.y);
            ((h2*)&ow)[1] = pkh(wa.z, wa.w);
            ((h2*)&ow)[2] = pkh(wb.x, wb.y);
            ((h2*)&ow)[3] = pkh(wb.z, wb.w);
            *(float4*)&Bs2[lrow][(tid & 3) * 4] = ow;
        }
        __syncthreads();
        half8 a0 = *(const half8*)&As2[qm + fm][fq * 4];
        half8 a1 = *(const half8*)&As2[qm + 16 + fm][fq * 4];
        half8 b0 = *(const half8*)&Bs2[qn + fm][fq * 4];
        half8 b1 = *(const half8*)&Bs2[qn + 16 + fm][fq * 4];
        acc00 = __builtin_amdgcn_mfma_f32_16x16x32_f16(a0, b0, acc00, 0, 0, 0);
        acc01 = __builtin_amdgcn_mfma_f32_16x16x32_f16(a0, b1, acc01, 0, 0, 0);
        acc10 = __builtin_amdgcn_mfma_f32_16x16x32_f16(a1, b0, acc10, 0, 0, 0);
        acc11 = __builtin_amdgcn_mfma_f32_16x16x32_f16(a1, b1, acc11, 0, 0, 0);
        __syncthreads();
    }

    const int g0 = col0 + qn + fm;
    const int g1 = g0 + 16;
    const float bb0 = bi[g0] + bh[g0];
    const float bb1 = bi[g1] + bh[g1];
    const int m0 = row0 + qm + fq * 4;
    #pragma unroll
    for (int r = 0; r < 4; r++) {
        int ma = m0 + r, mb = m0 + 16 + r;
        C[((size_t)(ma >> 2) * Gn + g0) * 4 + (ma & 3)] = (_Float16)(acc00[r] + bb0);
        C[((size_t)(ma >> 2) * Gn + g1) * 4 + (ma & 3)] = (_Float16)(acc01[r] + bb1);
        C[((size_t)(mb >> 2) * Gn + g0) * 4 + (mb & 3)] = (_Float16)(acc10[r] + bb0);
        C[((size_t)(mb >> 2) * Gn + g1) * 4 + (mb & 3)] = (_Float16)(acc11[r] + bb1);
    }
}

// ---------------------------------------------------------------------------
// scan256 v5: R12 structure + SPLIT ACCUMULATORS (4 partials per gate,
// chain depth 32 -> 8) to attack the ~1080-cyc non-issue tick residue
// (R14 showed lockstep waves can't fill it; theory: fdot2 dep-chain).
// ---------------------------------------------------------------------------
__global__ __launch_bounds__(256)
__attribute__((amdgpu_waves_per_eu(1, 2)))
void scan256(
    const _Float16* __restrict__ pre,   // pre4 quad-interleaved, fp16
    const float* __restrict__ w_hh,     // [512, 128] fp32 (this layer)
    _Float16* __restrict__ hs16)        // [B, Tn, 128] fp16 out
{
    const int b    = blockIdx.x;
    const int tid  = threadIdx.x;
    const int lane = tid & 63;
    const int wv   = tid >> 6;
    const int kq   = lane & 1;              // k-half
    const int u    = wv * 32 + (lane >> 1); // hidden unit (128 unique)

    __shared__ h2 hbuf[2][Hn / 2];
    __shared__ _Float16 hstage[2][16][Hn];  // 8 KB trajectory staging
    __shared__ float lds_pad[19456];        // 76 KiB occupancy limiter

    if (pre == nullptr) {                   // never true; keeps pad live
        lds_pad[tid] = (float)tid;
        __syncthreads();
        ((float*)hs16)[tid] = lds_pad[(tid * 7) & 19455];
    }

    const float* rI = w_hh + (size_t)(0 * Hn + u) * Hn + kq * 64;
    const float* rF = w_hh + (size_t)(1 * Hn + u) * Hn + kq * 64;
    const float* rG = w_hh + (size_t)(2 * Hn + u) * Hn + kq * 64;
    const float* rO = w_hh + (size_t)(3 * Hn + u) * Hn + kq * 64;
    DECL16(wiA, rI) DECL16(wiB, (rI + 32))
    DECL16(wfA, rF) DECL16(wfB, (rF + 32))
    DECL16(wgA, rG) DECL16(wgB, (rG + 32))
    DECL16(woA, rO) DECL16(woB, (rO + 32))
    KEEP16(wiA) KEEP16(wiB) KEEP16(wfA) KEEP16(wfB)
    KEEP16(wgA) KEEP16(wgB) KEEP16(woA) KEEP16(woB)

    if (tid < Hn / 2) hbuf[0][tid] = pkh(0.f, 0.f);
    __syncthreads();

    // quad-view of pre4: qq[qr*Gn + g*128 + u] = h4{ticks 4qr..4qr+3}
    const h4* qq = (const h4*)pre + (size_t)(b * 128) * Gn + u;
    _Float16* hsb = hs16 + (size_t)b * Tn * Hn;

    // pre-mask: only the kq==0 lane of each pair carries the pre/bias seed
    const float ms = (kq == 0) ? 1.f : 0.f;

    h4 qI0 = qq[0],   qF0 = qq[128],      qG0 = qq[256],      qO0 = qq[384];
    h4 qI1 = qq[Gn],  qF1 = qq[Gn + 128], qG1 = qq[Gn + 256], qO1 = qq[Gn + 384];
    const h4* pld = qq + 2 * (size_t)Gn;

    float cr = 0.f;

    auto body = [&](int t, float vI, float vF, float vG, float vO) {
        const h2* hrow = &hbuf[t & 1][kq * 32];
        half8 hA = LD8H(hrow);      half8 hB = LD8H(hrow + 4);
        half8 hC = LD8H(hrow + 8);  half8 hD = LD8H(hrow + 12);
        half8 hE = LD8H(hrow + 16); half8 hF_ = LD8H(hrow + 20);
        half8 hG_ = LD8H(hrow + 24); half8 hH_ = LD8H(hrow + 28);
        EXTRACT16(hvA, hA, hB, hC, hD)
        EXTRACT16(hvB, hE, hF_, hG_, hH_)

        // 4 independent partials per gate: chain depth 8
        float aI = vI,  aF = vF,  aG = vG,  aO = vO;   // A j0-7 (+ pre seed)
        float bI = 0.f, bF = 0.f, bG = 0.f, bO = 0.f;  // A j8-15
        float cI = 0.f, cF = 0.f, cG = 0.f, cO = 0.f;  // B j0-7
        float dI = 0.f, dF = 0.f, dG = 0.f, dO = 0.f;  // B j8-15

        DOTA_P(0,aI,aF,aG,aO)  DOTA_P(1,aI,aF,aG,aO)
        DOTA_P(2,aI,aF,aG,aO)  DOTA_P(3,aI,aF,aG,aO)
        DOTA_P(4,aI,aF,aG,aO)  DOTA_P(5,aI,aF,aG,aO)
        DOTA_P(6,aI,aF,aG,aO)  DOTA_P(7,aI,aF,aG,aO)
        DOTA_P(8,bI,bF,bG,bO)  DOTA_P(9,bI,bF,bG,bO)
        DOTA_P(10,bI,bF,bG,bO) DOTA_P(11,bI,bF,bG,bO)
        DOTA_P(12,bI,bF,bG,bO) DOTA_P(13,bI,bF,bG,bO)
        DOTA_P(14,bI,bF,bG,bO) DOTA_P(15,bI,bF,bG,bO)
        DOTB_P(0,cI,cF,cG,cO)  DOTB_P(1,cI,cF,cG,cO)
        DOTB_P(2,cI,cF,cG,cO)  DOTB_P(3,cI,cF,cG,cO)
        DOTB_P(4,cI,cF,cG,cO)  DOTB_P(5,cI,cF,cG,cO)
        DOTB_P(6,cI,cF,cG,cO)  DOTB_P(7,cI,cF,cG,cO)
        DOTB_P(8,dI,dF,dG,dO)  DOTB_P(9,dI,dF,dG,dO)
        DOTB_P(10,dI,dF,dG,dO) DOTB_P(11,dI,dF,dG,dO)
        DOTB_P(12,dI,dF,dG,dO) DOTB_P(13,dI,dF,dG,dO)
        DOTB_P(14,dI,dF,dG,dO) DOTB_P(15,dI,dF,dG,dO)

        // tree combine (2 levels) then pair butterfly
        aI = (aI + bI) + (cI + dI);
        aF = (aF + bF) + (cF + dF);
        aG = (aG + bG) + (cG + dG);
        aO = (aO + bO) + (cO + dO);

        DPPADD(aI, 0xB1) DPPADD(aF, 0xB1) DPPADD(aG, 0xB1) DPPADD(aO, 0xB1)

        float iv = sigm(aI);
        float fv = sigm(aF);
        float gv = tanh_fast(aG);
        float ov = sigm(aO);
        cr = fv * cr + iv * gv;
        float hnew = ov * tanh_fast(cr);
        _Float16 hh = (_Float16)hnew;
        if (kq == 0) {
            ((_Float16*)hbuf[(t + 1) & 1])[u] = hh;       // next-tick h
            hstage[(t >> 4) & 1][t & 15][u] = hh;         // traj staging
        }
        BAR_LDS();
    };

    // flush chunk ch (ticks 16ch..16ch+15) to global, coalesced b128.
    auto flush = [&](int ch) {
        const float4* src = (const float4*)&hstage[ch & 1][0][0];
        float4 v = src[tid];
        *(float4*)(hsb + (size_t)ch * 16 * Hn + tid * 8) = v;
    };

    // 128 quads: 126 steady + 2 epilogue. Flush after every 4th quad.
    for (int qr = 0; qr < 126; qr++) {
        body(4 * qr,     ms * (float)qI0.x, ms * (float)qF0.x,
                         ms * (float)qG0.x, ms * (float)qO0.x);
        body(4 * qr + 1, ms * (float)qI0.y, ms * (float)qF0.y,
                         ms * (float)qG0.y, ms * (float)qO0.y);
        body(4 * qr + 2, ms * (float)qI0.z, ms * (float)qF0.z,
                         ms * (float)qG0.z, ms * (float)qO0.z);
        body(4 * qr + 3, ms * (float)qI0.w, ms * (float)qF0.w,
                         ms * (float)qG0.w, ms * (float)qO0.w);
        if ((qr & 3) == 3) flush(qr >> 2);
        qI0 = qI1; qF0 = qF1; qG0 = qG1; qO0 = qO1;
        qI1 = pld[0]; qF1 = pld[128]; qG1 = pld[256]; qO1 = pld[384];
        pld += Gn;
    }
    // qr = 126
    body(504, ms * (float)qI0.x, ms * (float)qF0.x,
              ms * (float)qG0.x, ms * (float)qO0.x);
    body(505, ms * (float)qI0.y, ms * (float)qF0.y,
              ms * (float)qG0.y, ms * (float)qO0.y);
    body(506, ms * (float)qI0.z, ms * (float)qF0.z,
              ms * (float)qG0.z, ms * (float)qO0.z);
    body(507, ms * (float)qI0.w, ms * (float)qF0.w,
              ms * (float)qG0.w, ms * (float)qO0.w);
    qI0 = qI1; qF0 = qF1; qG0 = qG1; qO0 = qO1;
    // qr = 127
    body(508, ms * (float)qI0.x, ms * (float)qF0.x,
              ms * (float)qG0.x, ms * (float)qO0.x);
    body(509, ms * (float)qI0.y, ms * (float)qF0.y,
              ms * (float)qG0.y, ms * (float)qO0.y);
    body(510, ms * (float)qI0.z, ms * (float)qF0.z,
              ms * (float)qG0.z, ms * (float)qO0.z);
    body(511, ms * (float)qI0.w, ms * (float)qF0.w,
              ms * (float)qG0.w, ms * (float)qO0.w);
    flush(31);
}

// ---------------------------------------------------------------------------
// Attention pooling + MLP head (reads fp16 hs). One block per batch item.
// ---------------------------------------------------------------------------
__global__ __launch_bounds__(256) void head_kernel(
    const _Float16* __restrict__ hs16,
    const float* __restrict__ w_attn, const float* __restrict__ b_attn,
    const float* __restrict__ w1, const float* __restrict__ b1,
    const float* __restrict__ w2, const float* __restrict__ b2,
    float* __restrict__ out)
{
    const int b = blockIdx.x;
    const int tid = threadIdx.x;
    __shared__ h2 wa2[Hn / 2];
    __shared__ __align__(16) float sc[Tn];
    __shared__ __align__(16) float red[256];
    __shared__ __align__(16) float ctx_sh[Hn];
    __shared__ __align__(16) float h1_sh[64];

    if (tid < Hn / 2) wa2[tid] = pkh(w_attn[2 * tid], w_attn[2 * tid + 1]);
    __syncthreads();

    const _Float16* hb = hs16 + (size_t)b * Tn * Hn;

    for (int t = tid; t < Tn; t += 256) {
        const h2* hp = (const h2*)(hb + (size_t)t * Hn);
        float s = 0.f;
        #pragma unroll
        for (int k = 0; k < 64; k++) s = dot2(hp[k], wa2[k], s);
        sc[t] = s + b_attn[0];
    }
    __syncthreads();

    float m = fmaxf(sc[tid], sc[tid + 256]);
    red[tid] = m; __syncthreads();
    for (int s_ = 128; s_ > 0; s_ >>= 1) {
        if (tid < s_) red[tid] = fmaxf(red[tid], red[tid + s_]);
        __syncthreads();
    }
    float mx = red[0];
    __syncthreads();
    float e0 = __expf(sc[tid] - mx), e1 = __expf(sc[tid + 256] - mx);
    sc[tid] = e0; sc[tid + 256] = e1;
    red[tid] = e0 + e1; __syncthreads();
    for (int s_ = 128; s_ > 0; s_ >>= 1) {
        if (tid < s_) red[tid] += red[tid + s_];
        __syncthreads();
    }
    float inv = 1.f / red[0];
    __syncthreads();

    {
        int jj = tid & 127, half = tid >> 7;
        float a = 0.f;
        for (int t = half * 256; t < half * 256 + 256; t++)
            a += sc[t] * (float)hb[(size_t)t * Hn + jj];
        red[tid] = a;
        __syncthreads();
        if (tid < Hn) ctx_sh[tid] = (red[tid] + red[tid + Hn]) * inv;
        __syncthreads();
    }

    if (tid < 64) {
        const float4* wvv = (const float4*)(w1 + (size_t)tid * Hn);
        const float4* cv = (const float4*)ctx_sh;
        float s = 0.f;
        #pragma unroll
        for (int k = 0; k < 32; k++) {
            float4 a = wvv[k], c = cv[k];
            s += a.x * c.x + a.y * c.y + a.z * c.z + a.w * c.w;
        }
        h1_sh[tid] = fmaxf(s + b1[tid], 0.f);
    }
    __syncthreads();

    if (tid < 4) {
        float s = 0.f;
        const float* wvv = w2 + tid * 64;
        #pragma unroll
        for (int k = 0; k < 64; k++) s += wvv[k] * h1_sh[k];
        out[b * 4 + tid] = s + b2[tid];
    }
}

// ---------------------------------------------------------------------------
extern "C" void kernel_launch(void* const* d_in, const int* in_sizes, int n_in,
                              void* d_out, int out_size, void* d_ws, size_t ws_size,
                              hipStream_t stream)
{
    const float* x        = (const float*)d_in[0];
    const float* w_ih0    = (const float*)d_in[1];
    const float* w_ih_rest= (const float*)d_in[2];
    const float* w_hh     = (const float*)d_in[3];
    const float* b_ih     = (const float*)d_in[4];
    const float* b_hh     = (const float*)d_in[5];
    const float* w_attn   = (const float*)d_in[6];
    const float* b_attn   = (const float*)d_in[7];
    const float* w1       = (const float*)d_in[8];
    const float* b1       = (const float*)d_in[9];
    const float* w2       = (const float*)d_in[10];
    const float* b2       = (const float*)d_in[11];
    float* out = (float*)d_out;

    const size_t nHS  = (size_t)Bn * Tn * Hn;       // 8,388,608
    const size_t nPRE = (size_t)Bn * Tn * Gn;       // 33,554,432 (fp16)

    _Float16* preh = (_Float16*)d_ws;
    _Float16* hs0  = preh + nPRE;
    _Float16* hs1  = hs0 + nHS;
    _Float16* hs2  = hs1 + nHS;
    // total ~117 MB fp16

    // layer 0: A = x (fp32, converted inline), W = w_ih0 (fp32)
    gemm_pre<float><<<dim3(Bn * Tn / 64, 8), 256, 0, stream>>>(
        x, Dn, Tn * Dn, 0, 9, w_ih0, b_ih, b_hh, preh);
    scan256<<<Bn, 256, 0, stream>>>(preh, w_hh, hs0);

    // layer 1: A = hs0 (fp16), W = w_ih_rest[0] (fp32)
    gemm_pre<_Float16><<<dim3(Bn * Tn / 64, 8), 256, 0, stream>>>(
        hs0, Hn, Tn * Hn, 0, 9, w_ih_rest,
        b_ih + Gn, b_hh + Gn, preh);
    scan256<<<Bn, 256, 0, stream>>>(preh, w_hh + (size_t)Gn * Hn, hs1);

    // layer 2: A = hs1 (fp16), W = w_ih_rest[1] (fp32)
    gemm_pre<_Float16><<<dim3(Bn * Tn / 64, 8), 256, 0, stream>>>(
        hs1, Hn, Tn * Hn, 0, 9, w_ih_rest + (size_t)Gn * Hn,
        b_ih + 2 * Gn, b_hh + 2 * Gn, preh);
    scan256<<<Bn, 256, 0, stream>>>(preh, w_hh + 2 * (size_t)Gn * Hn, hs2);

    head_kernel<<<Bn, 256, 0, stream>>>(hs2, w_attn, b_attn, w1, b1, w2, b2, out);
}

// Round 16
// 893.993 us; speedup vs baseline: 1.1712x; 1.1712x over previous
//
#include <hip/hip_runtime.h>
#include <math.h>

#define Bn 128
#define Tn 512
#define Dn 32
#define Hn 128
#define Gn 512   // 4*H
#define Ln 3

// LDS-only barrier: does NOT drain vmcnt.
#define BAR_LDS() asm volatile("s_waitcnt lgkmcnt(0)\n\ts_barrier" ::: "memory")

typedef _Float16 h2 __attribute__((ext_vector_type(2)));
typedef _Float16 h4 __attribute__((ext_vector_type(4)));
typedef _Float16 half8 __attribute__((ext_vector_type(8)));   // MFMA A/B frag
typedef float f32x4 __attribute__((ext_vector_type(4)));      // MFMA acc

__device__ __forceinline__ float dot2(h2 a, h2 b, float c) {
    return __builtin_amdgcn_fdot2(a, b, c, false);
}
__device__ __forceinline__ h2 pkh(float a, float b) {
    h2 r; r.x = (_Float16)a; r.y = (_Float16)b; return r;
}
__device__ __forceinline__ float sigm(float x) {
    return __builtin_amdgcn_rcpf(1.f + __expf(-x));
}
__device__ __forceinline__ float tanh_fast(float x) {
    return 1.f - 2.f * __builtin_amdgcn_rcpf(1.f + __expf(2.f * x));
}

// DPP quad_perm butterfly add. 0xB1 = lanes 2i<->2i+1. 0x4E = pair swap.
#define DPPADD(a, CTRL) { \
    int _t = __builtin_amdgcn_update_dpp(0, __builtin_bit_cast(int, a), \
                                         CTRL, 0xF, 0xF, true); \
    a += __builtin_bit_cast(float, _t); }

#define KEEPH(x) asm volatile("" : "+v"(x))
#define LD8H(p) (*(const half8*)(p))
#define H2OF(V, i) (((const h2*)&(V))[i])

#define DECL16(P, R) \
  h2 P##0=pkh((R)[0],(R)[1]),   P##1=pkh((R)[2],(R)[3]),   P##2=pkh((R)[4],(R)[5]),   P##3=pkh((R)[6],(R)[7]),   \
     P##4=pkh((R)[8],(R)[9]),   P##5=pkh((R)[10],(R)[11]), P##6=pkh((R)[12],(R)[13]), P##7=pkh((R)[14],(R)[15]), \
     P##8=pkh((R)[16],(R)[17]), P##9=pkh((R)[18],(R)[19]), P##10=pkh((R)[20],(R)[21]),P##11=pkh((R)[22],(R)[23]),\
     P##12=pkh((R)[24],(R)[25]),P##13=pkh((R)[26],(R)[27]),P##14=pkh((R)[28],(R)[29]),P##15=pkh((R)[30],(R)[31]);
#define KEEP16(P) \
  KEEPH(P##0); KEEPH(P##1); KEEPH(P##2); KEEPH(P##3); KEEPH(P##4); KEEPH(P##5); \
  KEEPH(P##6); KEEPH(P##7); KEEPH(P##8); KEEPH(P##9); KEEPH(P##10); KEEPH(P##11); \
  KEEPH(P##12); KEEPH(P##13); KEEPH(P##14); KEEPH(P##15);

#define EXTRACT16(P, A, B, C, D) \
  h2 P##0 = H2OF(A,0), P##1 = H2OF(A,1), P##2  = H2OF(A,2), P##3  = H2OF(A,3), \
     P##4 = H2OF(B,0), P##5 = H2OF(B,1), P##6  = H2OF(B,2), P##7  = H2OF(B,3), \
     P##8 = H2OF(C,0), P##9 = H2OF(C,1), P##10 = H2OF(C,2), P##11 = H2OF(C,3), \
     P##12= H2OF(D,0), P##13= H2OF(D,1), P##14 = H2OF(D,2), P##15 = H2OF(D,3);

// pair-split dots (scan256): h halves A,B
#define DOTA(j) { \
    aI = dot2(hvA##j, wiA##j, aI);  aF = dot2(hvA##j, wfA##j, aF); \
    aG = dot2(hvA##j, wgA##j, aG);  aO = dot2(hvA##j, woA##j, aO); }
#define DOTB(j) { \
    aI = dot2(hvB##j, wiB##j, aI);  aF = dot2(hvB##j, wfB##j, aF); \
    aG = dot2(hvB##j, wgB##j, aG);  aO = dot2(hvB##j, woB##j, aO); }
// quad-split dots (pipe): hh on hv, ih on pv
#define DOT4V(j) { \
    aI = dot2(hv##j, wi##j, aI);  aF = dot2(hv##j, wf##j, aF); \
    aG = dot2(hv##j, wg##j, aG);  aO = dot2(hv##j, wo##j, aO); }
#define DOT4Y(j) { \
    aI = dot2(pv##j, yi##j, aI);  aF = dot2(pv##j, yf##j, aF); \
    aG = dot2(pv##j, yg##j, aG);  aO = dot2(pv##j, yo##j, aO); }

// ---------------------------------------------------------------------------
// MFMA GEMM with inline dtype conversion (R12, verified). Output quad-
// interleaved pre4[((m>>2)*Gn + g)*4 + (m&3)].
// ---------------------------------------------------------------------------
template<typename TA>
__global__ __launch_bounds__(256) void gemm_pre(
    const TA* __restrict__ A, int K, int rowStrideB, int t0, int tlog,
    const float* __restrict__ W,
    const float* __restrict__ bi, const float* __restrict__ bh,
    _Float16* __restrict__ C)
{
    __shared__ h2 As2[64][20];
    __shared__ h2 Bs2[64][20];
    const int tid  = threadIdx.x;
    const int row0 = blockIdx.x * 64;
    const int col0 = blockIdx.y * 64;
    const int w    = tid >> 6;
    const int lane = tid & 63;
    const int qm   = (w >> 1) * 32;
    const int qn   = (w & 1) * 32;
    const int fm   = lane & 15;
    const int fq   = lane >> 4;
    const int tmask = (1 << tlog) - 1;
    const int lrow = tid >> 2;
    const int lk   = (tid & 3) * 8;

    f32x4 acc00 = {0,0,0,0}, acc01 = {0,0,0,0};
    f32x4 acc10 = {0,0,0,0}, acc11 = {0,0,0,0};

    for (int k0 = 0; k0 < K; k0 += 32) {
        {
            int rg = row0 + lrow;
            int b_idx = rg >> tlog, tt = rg & tmask;
            const TA* ap = A + (size_t)b_idx * rowStrideB +
                           (size_t)(t0 + tt) * K + (k0 + lk);
            if constexpr (sizeof(TA) == 2) {
                *(float4*)&As2[lrow][(tid & 3) * 4] = *(const float4*)ap;
            } else {
                float4 va = *(const float4*)ap;
                float4 vb = *(const float4*)(ap + 4);
                float4 o;
                ((h2*)&o)[0] = pkh(va.x, va.y);
                ((h2*)&o)[1] = pkh(va.z, va.w);
                ((h2*)&o)[2] = pkh(vb.x, vb.y);
                ((h2*)&o)[3] = pkh(vb.z, vb.w);
                *(float4*)&As2[lrow][(tid & 3) * 4] = o;
            }
            const float* wp = W + (size_t)(col0 + lrow) * K + (k0 + lk);
            float4 wa = *(const float4*)wp;
            float4 wb = *(const float4*)(wp + 4);
            float4 ow;
            ((h2*)&ow)[0] = pkh(wa.x, wa.y);
            ((h2*)&ow)[1] = pkh(wa.z, wa.w);
            ((h2*)&ow)[2] = pkh(wb.x, wb.y);
            ((h2*)&ow)[3] = pkh(wb.z, wb.w);
            *(float4*)&Bs2[lrow][(tid & 3) * 4] = ow;
        }
        __syncthreads();
        half8 a0 = *(const half8*)&As2[qm + fm][fq * 4];
        half8 a1 = *(const half8*)&As2[qm + 16 + fm][fq * 4];
        half8 b0 = *(const half8*)&Bs2[qn + fm][fq * 4];
        half8 b1 = *(const half8*)&Bs2[qn + 16 + fm][fq * 4];
        acc00 = __builtin_amdgcn_mfma_f32_16x16x32_f16(a0, b0, acc00, 0, 0, 0);
        acc01 = __builtin_amdgcn_mfma_f32_16x16x32_f16(a0, b1, acc01, 0, 0, 0);
        acc10 = __builtin_amdgcn_mfma_f32_16x16x32_f16(a1, b0, acc10, 0, 0, 0);
        acc11 = __builtin_amdgcn_mfma_f32_16x16x32_f16(a1, b1, acc11, 0, 0, 0);
        __syncthreads();
    }

    const int g0 = col0 + qn + fm;
    const int g1 = g0 + 16;
    const float bb0 = bi[g0] + bh[g0];
    const float bb1 = bi[g1] + bh[g1];
    const int m0 = row0 + qm + fq * 4;
    #pragma unroll
    for (int r = 0; r < 4; r++) {
        int ma = m0 + r, mb = m0 + 16 + r;
        C[((size_t)(ma >> 2) * Gn + g0) * 4 + (ma & 3)] = (_Float16)(acc00[r] + bb0);
        C[((size_t)(ma >> 2) * Gn + g1) * 4 + (ma & 3)] = (_Float16)(acc01[r] + bb1);
        C[((size_t)(mb >> 2) * Gn + g0) * 4 + (mb & 3)] = (_Float16)(acc10[r] + bb0);
        C[((size_t)(mb >> 2) * Gn + g1) * 4 + (mb & 3)] = (_Float16)(acc11[r] + bb1);
    }
}

// ---------------------------------------------------------------------------
// pipe: cross-CU 2-layer wavefront. grid (128,2) x 512 thr, 1 block/CU via
// 80KB LDS pad -> all 256 blocks co-resident (deadlock-free, deps acyclic).
// y=0 (producer, layer 0): quad-split tick (R3-verified) reading quad-packed
//   pre0; h0 chunk-flushed (16 ticks) to hs0 + release-flag publish.
// y=1 (consumer, layer 1): quad-split tick + fused ih dots on h0 read from a
//   16-tick LDS-staged chunk ring (loads issue a full chunk ahead -> remote
//   L2/HBM latency OFF the serial path; this was R4-6's fatal flaw). Gates
//   on the producer flag once per chunk. h1 chunk-flushed to hs1.
// ---------------------------------------------------------------------------
__global__ __launch_bounds__(512)
__attribute__((amdgpu_waves_per_eu(2)))
void pipe(
    const _Float16* __restrict__ pre0,  // quad-interleaved layer-0 pre
    const float* __restrict__ w_hh,     // [L][512][128] fp32
    const float* __restrict__ wih1,     // w_ih_rest[0]: [512][128] fp32
    const float* __restrict__ b_ih, const float* __restrict__ b_hh, // [L][512]
    _Float16* __restrict__ hs0,         // [B][Tn][128] layer-0 out
    _Float16* __restrict__ hs1,         // [B][Tn][128] layer-1 out
    int* __restrict__ flags)            // [B] chunks published by producer
{
    const int b    = blockIdx.x;
    const int layer= blockIdx.y;           // 0 producer / 1 consumer
    const int tid  = threadIdx.x;
    const int lane = tid & 63;
    const int wv   = tid >> 6;
    const int kq4  = lane & 3;
    const int u    = wv * 16 + (lane >> 2);   // unit 0..127 over 8 waves

    __shared__ h2 hb[2][Hn / 2];              // recurrent h ring
    __shared__ _Float16 hstage[2][16][Hn];    // 8 KB out-chunk staging
    __shared__ _Float16 pL[2][16][Hn];        // 8 KB consumer h0 chunk ring
    __shared__ float lds_pad[20480];          // 80 KiB occupancy limiter

    if (pre0 == nullptr) {                    // never true; keeps pad live
        lds_pad[tid] = (float)tid;
        __syncthreads();
        ((float*)hs0)[tid] = lds_pad[(tid * 7) & 20479];
    }

    // recurrent weights for this layer (quad-split: 64 h2)
    const float* whl = w_hh + (size_t)layer * Gn * Hn;
    const float* rI = whl + (size_t)(0 * Hn + u) * Hn + kq4 * 32;
    const float* rF = whl + (size_t)(1 * Hn + u) * Hn + kq4 * 32;
    const float* rG = whl + (size_t)(2 * Hn + u) * Hn + kq4 * 32;
    const float* rO = whl + (size_t)(3 * Hn + u) * Hn + kq4 * 32;
    DECL16(wi, rI) DECL16(wf, rF) DECL16(wg, rG) DECL16(wo, rO)
    KEEP16(wi) KEEP16(wf) KEEP16(wg) KEEP16(wo)

    if (tid < Hn / 2) hb[0][tid] = pkh(0.f, 0.f);

    float cr = 0.f;

    if (layer == 0) {
        // ======================= PRODUCER (layer 0) =======================
        __syncthreads();
        const float mI = (kq4 == 0) ? 1.f : 0.f;
        const float mF = (kq4 == 1) ? 1.f : 0.f;
        const float mG = (kq4 == 2) ? 1.f : 0.f;
        const float mO = (kq4 == 3) ? 1.f : 0.f;

        // single per-lane pre stream: gate kq4 of unit u, quad-packed
        const h4* qq = (const h4*)pre0 + (size_t)(b * 128) * Gn + kq4 * Hn + u;
        _Float16* hs0b = hs0 + (size_t)b * Tn * Hn;

        h4 q0 = qq[0];
        h4 q1 = qq[Gn];
        const h4* pld = qq + 2 * (size_t)Gn;

        auto tick = [&](int t, float pv) {
            const h2* hrow = &hb[t & 1][kq4 * 16];
            half8 hA = LD8H(hrow);     half8 hB = LD8H(hrow + 4);
            half8 hC = LD8H(hrow + 8); half8 hD = LD8H(hrow + 12);
            EXTRACT16(hv, hA, hB, hC, hD)

            float aI = 0.f, aF = 0.f, aG = 0.f, aO = 0.f;
            DOT4V(0)  DOT4V(1)  DOT4V(2)  DOT4V(3)
            DOT4V(4)  DOT4V(5)  DOT4V(6)  DOT4V(7)
            DOT4V(8)  DOT4V(9)  DOT4V(10) DOT4V(11)
            DOT4V(12) DOT4V(13) DOT4V(14) DOT4V(15)

            aI = fmaf(pv, mI, aI);
            aF = fmaf(pv, mF, aF);
            aG = fmaf(pv, mG, aG);
            aO = fmaf(pv, mO, aO);

            DPPADD(aI, 0xB1) DPPADD(aF, 0xB1) DPPADD(aG, 0xB1) DPPADD(aO, 0xB1)
            DPPADD(aI, 0x4E) DPPADD(aF, 0x4E) DPPADD(aG, 0x4E) DPPADD(aO, 0x4E)

            float iv = sigm(aI);
            float fv = sigm(aF);
            float gv = tanh_fast(aG);
            float ov = sigm(aO);
            cr = fv * cr + iv * gv;
            float hnew = ov * tanh_fast(cr);
            _Float16 hh = (_Float16)hnew;
            if (kq4 == 0) {
                ((_Float16*)hb[(t + 1) & 1])[u] = hh;
                hstage[(t >> 4) & 1][t & 15][u] = hh;
            }
            BAR_LDS();
        };

        auto flush_pub = [&](int ch) {
            if (tid < 256) {
                float4 v = ((const float4*)&hstage[ch & 1][0][0])[tid];
                *(float4*)(hs0b + (size_t)ch * 16 * Hn + tid * 8) = v;
            }
            asm volatile("s_waitcnt vmcnt(0)" ::: "memory");
            __syncthreads();
            if (tid == 0)
                __hip_atomic_store(flags + b, ch + 1, __ATOMIC_RELEASE,
                                   __HIP_MEMORY_SCOPE_AGENT);
        };

        for (int qr = 0; qr < 126; qr++) {
            tick(4 * qr,     (float)q0.x);
            tick(4 * qr + 1, (float)q0.y);
            tick(4 * qr + 2, (float)q0.z);
            tick(4 * qr + 3, (float)q0.w);
            if ((qr & 3) == 3) flush_pub(qr >> 2);
            q0 = q1;
            q1 = *pld; pld += Gn;
        }
        // qr = 126 (no flush; 126&3==2)
        tick(504, (float)q0.x); tick(505, (float)q0.y);
        tick(506, (float)q0.z); tick(507, (float)q0.w);
        q0 = q1;
        // qr = 127
        tick(508, (float)q0.x); tick(509, (float)q0.y);
        tick(510, (float)q0.z); tick(511, (float)q0.w);
        flush_pub(31);
    } else {
        // ======================= CONSUMER (layer 1) =======================
        // ih weights (quad-split: 64 h2)
        const float* yIr = wih1 + (size_t)(0 * Hn + u) * Hn + kq4 * 32;
        const float* yFr = wih1 + (size_t)(1 * Hn + u) * Hn + kq4 * 32;
        const float* yGr = wih1 + (size_t)(2 * Hn + u) * Hn + kq4 * 32;
        const float* yOr = wih1 + (size_t)(3 * Hn + u) * Hn + kq4 * 32;
        DECL16(yi, yIr) DECL16(yf, yFr) DECL16(yg, yGr) DECL16(yo, yOr)
        KEEP16(yi) KEEP16(yf) KEEP16(yg) KEEP16(yo)

        const float bI1 = b_ih[Gn + 0 * Hn + u] + b_hh[Gn + 0 * Hn + u];
        const float bF1 = b_ih[Gn + 1 * Hn + u] + b_hh[Gn + 1 * Hn + u];
        const float bG1 = b_ih[Gn + 2 * Hn + u] + b_hh[Gn + 2 * Hn + u];
        const float bO1 = b_ih[Gn + 3 * Hn + u] + b_hh[Gn + 3 * Hn + u];

        const _Float16* hs0b = hs0 + (size_t)b * Tn * Hn;
        _Float16* hs1b = hs1 + (size_t)b * Tn * Hn;

        int avail = 0;
        auto gate = [&](int need) {
            if (avail >= need) return;
            do {
                int a0 = 0;
                if (lane == 0)
                    a0 = __hip_atomic_load(flags + b, __ATOMIC_ACQUIRE,
                                           __HIP_MEMORY_SCOPE_AGENT);
                avail = __builtin_amdgcn_readfirstlane(a0);
                if (avail < need) __builtin_amdgcn_s_sleep(8);
            } while (avail < need);
        };

        auto tick = [&](int t) {
            const h2* h1row = &hb[t & 1][kq4 * 16];
            half8 hA = LD8H(h1row);     half8 hB = LD8H(h1row + 4);
            half8 hC = LD8H(h1row + 8); half8 hD = LD8H(h1row + 12);
            EXTRACT16(hv, hA, hB, hC, hD)
            const h2* h0row = (const h2*)&pL[(t >> 4) & 1][t & 15][kq4 * 32];
            half8 pA = LD8H(h0row);     half8 pB = LD8H(h0row + 4);
            half8 pC = LD8H(h0row + 8); half8 pD = LD8H(h0row + 12);
            EXTRACT16(pv, pA, pB, pC, pD)

            float aI = 0.f, aF = 0.f, aG = 0.f, aO = 0.f;
            DOT4V(0)  DOT4V(1)  DOT4V(2)  DOT4V(3)
            DOT4V(4)  DOT4V(5)  DOT4V(6)  DOT4V(7)
            DOT4V(8)  DOT4V(9)  DOT4V(10) DOT4V(11)
            DOT4V(12) DOT4V(13) DOT4V(14) DOT4V(15)
            DOT4Y(0)  DOT4Y(1)  DOT4Y(2)  DOT4Y(3)
            DOT4Y(4)  DOT4Y(5)  DOT4Y(6)  DOT4Y(7)
            DOT4Y(8)  DOT4Y(9)  DOT4Y(10) DOT4Y(11)
            DOT4Y(12) DOT4Y(13) DOT4Y(14) DOT4Y(15)

            DPPADD(aI, 0xB1) DPPADD(aF, 0xB1) DPPADD(aG, 0xB1) DPPADD(aO, 0xB1)
            DPPADD(aI, 0x4E) DPPADD(aF, 0x4E) DPPADD(aG, 0x4E) DPPADD(aO, 0x4E)

            float iv = sigm(aI + bI1);
            float fv = sigm(aF + bF1);
            float gv = tanh_fast(aG + bG1);
            float ov = sigm(aO + bO1);
            cr = fv * cr + iv * gv;
            float hnew = ov * tanh_fast(cr);
            _Float16 hh = (_Float16)hnew;
            if (kq4 == 0) {
                ((_Float16*)hb[(t + 1) & 1])[u] = hh;
                hstage[(t >> 4) & 1][t & 15][u] = hh;
            }
            BAR_LDS();
        };

        // prologue: stage chunk 0
        gate(1);
        if (tid < 256) {
            float4 v = *(const float4*)(hs0b + tid * 8);
            *(float4*)((_Float16*)&pL[0][0][0] + tid * 8) = v;
        }
        __syncthreads();

        for (int c = 0; c < 32; c++) {
            // prefetch-stage chunk c+1 (reads of pL[(c+1)&1] ended in c-1)
            if (c + 1 < 32) {
                gate(c + 2);
                if (tid < 256) {
                    float4 v = *(const float4*)(hs0b +
                                (size_t)(c + 1) * 16 * Hn + tid * 8);
                    *(float4*)((_Float16*)&pL[(c + 1) & 1][0][0] + tid * 8) = v;
                }
            }
            #pragma unroll
            for (int tt = 0; tt < 16; tt++) tick(16 * c + tt);
            // flush h1 chunk c (all hstage writes visible after last barrier)
            if (tid < 256) {
                float4 v = ((const float4*)&hstage[c & 1][0][0])[tid];
                *(float4*)(hs1b + (size_t)c * 16 * Hn + tid * 8) = v;
            }
        }
    }
}

// ---------------------------------------------------------------------------
// scan256 (R12 v4, verified): layer-2 scan. Quad-pre + chunked traj store.
// ---------------------------------------------------------------------------
__global__ __launch_bounds__(256)
__attribute__((amdgpu_waves_per_eu(1, 2)))
void scan256(
    const _Float16* __restrict__ pre,   // pre4 quad-interleaved, fp16
    const float* __restrict__ w_hh,     // [512, 128] fp32 (this layer)
    _Float16* __restrict__ hs16)        // [B, Tn, 128] fp16 out
{
    const int b    = blockIdx.x;
    const int tid  = threadIdx.x;
    const int lane = tid & 63;
    const int wv   = tid >> 6;
    const int kq   = lane & 1;
    const int u    = wv * 32 + (lane >> 1);

    __shared__ h2 hbuf[2][Hn / 2];
    __shared__ _Float16 hstage[2][16][Hn];
    __shared__ float lds_pad[19456];

    if (pre == nullptr) {
        lds_pad[tid] = (float)tid;
        __syncthreads();
        ((float*)hs16)[tid] = lds_pad[(tid * 7) & 19455];
    }

    const float* rI = w_hh + (size_t)(0 * Hn + u) * Hn + kq * 64;
    const float* rF = w_hh + (size_t)(1 * Hn + u) * Hn + kq * 64;
    const float* rG = w_hh + (size_t)(2 * Hn + u) * Hn + kq * 64;
    const float* rO = w_hh + (size_t)(3 * Hn + u) * Hn + kq * 64;
    DECL16(wiA, rI) DECL16(wiB, (rI + 32))
    DECL16(wfA, rF) DECL16(wfB, (rF + 32))
    DECL16(wgA, rG) DECL16(wgB, (rG + 32))
    DECL16(woA, rO) DECL16(woB, (rO + 32))
    KEEP16(wiA) KEEP16(wiB) KEEP16(wfA) KEEP16(wfB)
    KEEP16(wgA) KEEP16(wgB) KEEP16(woA) KEEP16(woB)

    if (tid < Hn / 2) hbuf[0][tid] = pkh(0.f, 0.f);
    __syncthreads();

    const h4* qq = (const h4*)pre + (size_t)(b * 128) * Gn + u;
    _Float16* hsb = hs16 + (size_t)b * Tn * Hn;

    const float ms = (kq == 0) ? 1.f : 0.f;

    h4 qI0 = qq[0],   qF0 = qq[128],      qG0 = qq[256],      qO0 = qq[384];
    h4 qI1 = qq[Gn],  qF1 = qq[Gn + 128], qG1 = qq[Gn + 256], qO1 = qq[Gn + 384];
    const h4* pld = qq + 2 * (size_t)Gn;

    float cr = 0.f;

    auto body = [&](int t, float vI, float vF, float vG, float vO) {
        const h2* hrow = &hbuf[t & 1][kq * 32];
        half8 hA = LD8H(hrow);      half8 hB = LD8H(hrow + 4);
        half8 hC = LD8H(hrow + 8);  half8 hD = LD8H(hrow + 12);
        half8 hE = LD8H(hrow + 16); half8 hF_ = LD8H(hrow + 20);
        half8 hG_ = LD8H(hrow + 24); half8 hH_ = LD8H(hrow + 28);
        EXTRACT16(hvA, hA, hB, hC, hD)
        EXTRACT16(hvB, hE, hF_, hG_, hH_)

        float aI = vI, aF = vF, aG = vG, aO = vO;
        DOTA(0)  DOTA(1)  DOTA(2)  DOTA(3)
        DOTA(4)  DOTA(5)  DOTA(6)  DOTA(7)
        DOTA(8)  DOTA(9)  DOTA(10) DOTA(11)
        DOTA(12) DOTA(13) DOTA(14) DOTA(15)
        DOTB(0)  DOTB(1)  DOTB(2)  DOTB(3)
        DOTB(4)  DOTB(5)  DOTB(6)  DOTB(7)
        DOTB(8)  DOTB(9)  DOTB(10) DOTB(11)
        DOTB(12) DOTB(13) DOTB(14) DOTB(15)

        DPPADD(aI, 0xB1) DPPADD(aF, 0xB1) DPPADD(aG, 0xB1) DPPADD(aO, 0xB1)

        float iv = sigm(aI);
        float fv = sigm(aF);
        float gv = tanh_fast(aG);
        float ov = sigm(aO);
        cr = fv * cr + iv * gv;
        float hnew = ov * tanh_fast(cr);
        _Float16 hh = (_Float16)hnew;
        if (kq == 0) {
            ((_Float16*)hbuf[(t + 1) & 1])[u] = hh;
            hstage[(t >> 4) & 1][t & 15][u] = hh;
        }
        BAR_LDS();
    };

    auto flush = [&](int ch) {
        const float4* src = (const float4*)&hstage[ch & 1][0][0];
        float4 v = src[tid];
        *(float4*)(hsb + (size_t)ch * 16 * Hn + tid * 8) = v;
    };

    for (int qr = 0; qr < 126; qr++) {
        body(4 * qr,     ms * (float)qI0.x, ms * (float)qF0.x,
                         ms * (float)qG0.x, ms * (float)qO0.x);
        body(4 * qr + 1, ms * (float)qI0.y, ms * (float)qF0.y,
                         ms * (float)qG0.y, ms * (float)qO0.y);
        body(4 * qr + 2, ms * (float)qI0.z, ms * (float)qF0.z,
                         ms * (float)qG0.z, ms * (float)qO0.z);
        body(4 * qr + 3, ms * (float)qI0.w, ms * (float)qF0.w,
                         ms * (float)qG0.w, ms * (float)qO0.w);
        if ((qr & 3) == 3) flush(qr >> 2);
        qI0 = qI1; qF0 = qF1; qG0 = qG1; qO0 = qO1;
        qI1 = pld[0]; qF1 = pld[128]; qG1 = pld[256]; qO1 = pld[384];
        pld += Gn;
    }
    body(504, ms * (float)qI0.x, ms * (float)qF0.x,
              ms * (float)qG0.x, ms * (float)qO0.x);
    body(505, ms * (float)qI0.y, ms * (float)qF0.y,
              ms * (float)qG0.y, ms * (float)qO0.y);
    body(506, ms * (float)qI0.z, ms * (float)qF0.z,
              ms * (float)qG0.z, ms * (float)qO0.z);
    body(507, ms * (float)qI0.w, ms * (float)qF0.w,
              ms * (float)qG0.w, ms * (float)qO0.w);
    qI0 = qI1; qF0 = qF1; qG0 = qG1; qO0 = qO1;
    body(508, ms * (float)qI0.x, ms * (float)qF0.x,
              ms * (float)qG0.x, ms * (float)qO0.x);
    body(509, ms * (float)qI0.y, ms * (float)qF0.y,
              ms * (float)qG0.y, ms * (float)qO0.y);
    body(510, ms * (float)qI0.z, ms * (float)qF0.z,
              ms * (float)qG0.z, ms * (float)qO0.z);
    body(511, ms * (float)qI0.w, ms * (float)qF0.w,
              ms * (float)qG0.w, ms * (float)qO0.w);
    flush(31);
}

// ---------------------------------------------------------------------------
// Attention pooling + MLP head (reads fp16 hs). One block per batch item.
// ---------------------------------------------------------------------------
__global__ __launch_bounds__(256) void head_kernel(
    const _Float16* __restrict__ hs16,
    const float* __restrict__ w_attn, const float* __restrict__ b_attn,
    const float* __restrict__ w1, const float* __restrict__ b1,
    const float* __restrict__ w2, const float* __restrict__ b2,
    float* __restrict__ out)
{
    const int b = blockIdx.x;
    const int tid = threadIdx.x;
    __shared__ h2 wa2[Hn / 2];
    __shared__ __align__(16) float sc[Tn];
    __shared__ __align__(16) float red[256];
    __shared__ __align__(16) float ctx_sh[Hn];
    __shared__ __align__(16) float h1_sh[64];

    if (tid < Hn / 2) wa2[tid] = pkh(w_attn[2 * tid], w_attn[2 * tid + 1]);
    __syncthreads();

    const _Float16* hb = hs16 + (size_t)b * Tn * Hn;

    for (int t = tid; t < Tn; t += 256) {
        const h2* hp = (const h2*)(hb + (size_t)t * Hn);
        float s = 0.f;
        #pragma unroll
        for (int k = 0; k < 64; k++) s = dot2(hp[k], wa2[k], s);
        sc[t] = s + b_attn[0];
    }
    __syncthreads();

    float m = fmaxf(sc[tid], sc[tid + 256]);
    red[tid] = m; __syncthreads();
    for (int s_ = 128; s_ > 0; s_ >>= 1) {
        if (tid < s_) red[tid] = fmaxf(red[tid], red[tid + s_]);
        __syncthreads();
    }
    float mx = red[0];
    __syncthreads();
    float e0 = __expf(sc[tid] - mx), e1 = __expf(sc[tid + 256] - mx);
    sc[tid] = e0; sc[tid + 256] = e1;
    red[tid] = e0 + e1; __syncthreads();
    for (int s_ = 128; s_ > 0; s_ >>= 1) {
        if (tid < s_) red[tid] += red[tid + s_];
        __syncthreads();
    }
    float inv = 1.f / red[0];
    __syncthreads();

    {
        int jj = tid & 127, half = tid >> 7;
        float a = 0.f;
        for (int t = half * 256; t < half * 256 + 256; t++)
            a += sc[t] * (float)hb[(size_t)t * Hn + jj];
        red[tid] = a;
        __syncthreads();
        if (tid < Hn) ctx_sh[tid] = (red[tid] + red[tid + Hn]) * inv;
        __syncthreads();
    }

    if (tid < 64) {
        const float4* wvv = (const float4*)(w1 + (size_t)tid * Hn);
        const float4* cv = (const float4*)ctx_sh;
        float s = 0.f;
        #pragma unroll
        for (int k = 0; k < 32; k++) {
            float4 a = wvv[k], c = cv[k];
            s += a.x * c.x + a.y * c.y + a.z * c.z + a.w * c.w;
        }
        h1_sh[tid] = fmaxf(s + b1[tid], 0.f);
    }
    __syncthreads();

    if (tid < 4) {
        float s = 0.f;
        const float* wvv = w2 + tid * 64;
        #pragma unroll
        for (int k = 0; k < 64; k++) s += wvv[k] * h1_sh[k];
        out[b * 4 + tid] = s + b2[tid];
    }
}

// ---------------------------------------------------------------------------
extern "C" void kernel_launch(void* const* d_in, const int* in_sizes, int n_in,
                              void* d_out, int out_size, void* d_ws, size_t ws_size,
                              hipStream_t stream)
{
    const float* x        = (const float*)d_in[0];
    const float* w_ih0    = (const float*)d_in[1];
    const float* w_ih_rest= (const float*)d_in[2];
    const float* w_hh     = (const float*)d_in[3];
    const float* b_ih     = (const float*)d_in[4];
    const float* b_hh     = (const float*)d_in[5];
    const float* w_attn   = (const float*)d_in[6];
    const float* b_attn   = (const float*)d_in[7];
    const float* w1       = (const float*)d_in[8];
    const float* b1       = (const float*)d_in[9];
    const float* w2       = (const float*)d_in[10];
    const float* b2       = (const float*)d_in[11];
    float* out = (float*)d_out;

    const size_t nHS  = (size_t)Bn * Tn * Hn;       // 8,388,608
    const size_t nPRE = (size_t)Bn * Tn * Gn;       // 33,554,432 (fp16)

    _Float16* preh = (_Float16*)d_ws;
    _Float16* hs0  = preh + nPRE;
    _Float16* hs1  = hs0 + nHS;
    _Float16* hs2  = hs1 + nHS;
    int* flags     = (int*)(hs2 + nHS);   // 128 ints
    // total ~117 MB

    hipMemsetAsync(flags, 0, Bn * sizeof(int), stream);

    // layer-0 pre-GEMM (x fp32 converted inline)
    gemm_pre<float><<<dim3(Bn * Tn / 64, 8), 256, 0, stream>>>(
        x, Dn, Tn * Dn, 0, 9, w_ih0, b_ih, b_hh, preh);

    // layers 0 + 1: cross-CU wavefront pipeline (256 CUs, all co-resident)
    pipe<<<dim3(Bn, 2), 512, 0, stream>>>(preh, w_hh, w_ih_rest,
                                          b_ih, b_hh, hs0, hs1, flags);

    // layer 2: pre-GEMM + scan
    gemm_pre<_Float16><<<dim3(Bn * Tn / 64, 8), 256, 0, stream>>>(
        hs1, Hn, Tn * Hn, 0, 9, w_ih_rest + (size_t)Gn * Hn,
        b_ih + 2 * Gn, b_hh + 2 * Gn, preh);
    scan256<<<Bn, 256, 0, stream>>>(preh, w_hh + 2 * (size_t)Gn * Hn, hs2);

    head_kernel<<<Bn, 256, 0, stream>>>(hs2, w_attn, b_attn, w1, b1, w2, b2, out);
}